// Round 1
// baseline (1931.726 us; speedup 1.0000x reference)
//
#include <hip/hip_runtime.h>
#include <math.h>

// Problem constants (fixed by setup_inputs): L=12 layers, B=16, V=4 views,
// H=12 heads, T=196 img tokens, S=197 (CLS + patches).
constexpr int L_ = 12, B_ = 16, V_ = 4, H_ = 12, T_ = 196, S_ = 197;
constexpr int BV_ = B_ * V_;        // 64
constexpr int NCHAIN = BV_ * H_;    // 768 independent (bv,h) chains

// ---------------------------------------------------------------------------
// Kernel 1: attention-rollout chain, row-0 only.
// last_row = e0^T * m[11] * m[10] * ... * m[0]  computed as repeated v <- v@M.
// One block per (bv,h) chain; thread t owns output column t.
// Reads each of the 11 lower-layer matrices exactly once, fully coalesced
// (lane t reads M[i*197 + t], consecutive across lanes for each row i).
// ---------------------------------------------------------------------------
__global__ __launch_bounds__(256) void chain_kernel(const float* __restrict__ views,
                                                    float* __restrict__ last) {
    const int chain = blockIdx.x;   // = bv*H + h
    const int t = threadIdx.x;
    __shared__ float vbuf[2][S_];

    const size_t mat = (size_t)S_ * S_;
    const size_t lstride = (size_t)NCHAIN * mat;  // layer stride in elements
    const float* base = views + (size_t)chain * mat;

    // init v = row 0 of layer L-1 (only row we ever need from that layer)
    if (t < S_) vbuf[0][t] = base[(size_t)(L_ - 1) * lstride + t];
    __syncthreads();

    int cur = 0;
    for (int l = L_ - 2; l >= 0; --l) {
        const float* M = base + (size_t)l * lstride + t;  // column t of layer l
        if (t < S_) {
            float acc = 0.f;
            #pragma unroll 8
            for (int i = 0; i < S_; ++i)
                acc = fmaf(vbuf[cur][i], M[(size_t)i * S_], acc);
            vbuf[1 - cur][t] = acc;   // writes other buffer: no race with reads
        }
        __syncthreads();
        cur = 1 - cur;
    }
    // last = v[1:]  (drop CLS column)
    if (t >= 1 && t < S_) last[(size_t)chain * T_ + (t - 1)] = vbuf[cur][t];
}

// ---------------------------------------------------------------------------
// Kernel 2: global 5x5 rollout chain -> per-view token budget.
// One thread per batch element b (16 active threads total; trivial work).
// counts = rint(softmax(max_h chain_row0[1:]) * T); counts[0] += T - sum.
// ---------------------------------------------------------------------------
__global__ void counts_kernel(const float* __restrict__ glob,
                              float* __restrict__ out_counts_f,
                              int* __restrict__ counts_i) {
    const int b = blockIdx.x * blockDim.x + threadIdx.x;
    if (b >= B_) return;
    const int G = V_ + 1;  // 5

    float gm[V_];
    for (int v = 0; v < V_; ++v) gm[v] = -INFINITY;

    for (int h = 0; h < H_; ++h) {
        float vcur[G], vnxt[G];
        const float* m_top = glob + (((size_t)(L_ - 1) * B_ + b) * H_ + h) * (G * G);
        for (int j = 0; j < G; ++j) vcur[j] = m_top[j];  // row 0 of layer L-1
        for (int l = L_ - 2; l >= 0; --l) {
            const float* M = glob + (((size_t)l * B_ + b) * H_ + h) * (G * G);
            for (int j = 0; j < G; ++j) {
                float a = 0.f;
                for (int i = 0; i < G; ++i) a = fmaf(vcur[i], M[i * G + j], a);
                vnxt[j] = a;
            }
            for (int j = 0; j < G; ++j) vcur[j] = vnxt[j];
        }
        for (int v = 0; v < V_; ++v) gm[v] = fmaxf(gm[v], vcur[v + 1]);
    }

    // softmax over V (=4), round half-to-even like jnp.round
    float mx = gm[0];
    for (int v = 1; v < V_; ++v) mx = fmaxf(mx, gm[v]);
    float e[V_], s = 0.f;
    for (int v = 0; v < V_; ++v) { e[v] = expf(gm[v] - mx); s += e[v]; }
    int c[V_], sum = 0;
    for (int v = 0; v < V_; ++v) { c[v] = (int)rintf(e[v] / s * (float)T_); sum += c[v]; }
    c[0] += T_ - sum;

    for (int v = 0; v < V_; ++v) {
        counts_i[b * V_ + v] = c[v];
        out_counts_f[b * V_ + v] = (float)c[v];
    }
}

// ---------------------------------------------------------------------------
// Kernel 3: max over heads -> last_map row; stable ascending rank-sort
// (O(T^2) per row, T=196 — trivial); emit topk ids with -1 padding.
// One block per (b,v) row.
// ---------------------------------------------------------------------------
__global__ __launch_bounds__(256) void topk_kernel(const float* __restrict__ last,
                                                   const int* __restrict__ counts_i,
                                                   float* __restrict__ out_topk,
                                                   float* __restrict__ out_lastmap) {
    const int bv = blockIdx.x;  // = b*V + v
    const int t = threadIdx.x;
    __shared__ float row[T_];
    __shared__ int order[T_];

    if (t < T_) {
        float m = -INFINITY;
        #pragma unroll
        for (int h = 0; h < H_; ++h)
            m = fmaxf(m, last[((size_t)bv * H_ + h) * T_ + t]);
        row[t] = m;
        out_lastmap[(size_t)bv * T_ + t] = m;
    }
    __syncthreads();

    if (t < T_) {
        const float x = row[t];
        int rank = 0;
        for (int u = 0; u < T_; ++u) {
            float y = row[u];
            rank += (y < x) || (y == x && u < t);  // stable ascending
        }
        order[rank] = t;
    }
    __syncthreads();

    if (t < T_) {
        const int cnt = counts_i[bv];
        out_topk[(size_t)bv * T_ + t] = (t >= T_ - cnt) ? (float)order[t] : -1.0f;
    }
}

// ---------------------------------------------------------------------------
extern "C" void kernel_launch(void* const* d_in, const int* in_sizes, int n_in,
                              void* d_out, int out_size, void* d_ws, size_t ws_size,
                              hipStream_t stream) {
    const float* views = (const float*)d_in[0];  // [L, B*V, H, S, S]
    const float* glob  = (const float*)d_in[1];  // [L, B, H, V+1, V+1]
    // d_in[2]=num_views, d_in[3]=img_tokens: fixed constants, hardcoded.

    float* out = (float*)d_out;
    float* out_topk    = out;                          // [B,V,T] as float
    float* out_counts  = out + (size_t)BV_ * T_;       // [B,V]   as float
    float* out_lastmap = out_counts + BV_;             // [B,V,T] float32

    float* ws_last   = (float*)d_ws;                         // NCHAIN*T floats (602 KB)
    int*   ws_counts = (int*)(ws_last + (size_t)NCHAIN * T_);// B*V ints

    hipLaunchKernelGGL(chain_kernel, dim3(NCHAIN), dim3(256), 0, stream, views, ws_last);
    hipLaunchKernelGGL(counts_kernel, dim3(1), dim3(64), 0, stream, glob, out_counts, ws_counts);
    hipLaunchKernelGGL(topk_kernel, dim3(BV_), dim3(256), 0, stream, ws_last, ws_counts, out_topk, out_lastmap);
}